// Round 5
// baseline (223.867 us; speedup 1.0000x reference)
//
#include <hip/hip_runtime.h>

typedef unsigned short u16;
typedef __bf16 bf16x8 __attribute__((ext_vector_type(8)));
typedef float f32x4 __attribute__((ext_vector_type(4)));

__device__ __forceinline__ float b2f(u16 v) {
    return __uint_as_float(((unsigned int)v) << 16);
}
__device__ __forceinline__ u16 f2b(float f) {
    unsigned int u = __float_as_uint(f);
    u += 0x7fffu + ((u >> 16) & 1u);   // RNE
    return (u16)(u >> 16);
}

// async global->LDS, 16B/lane. Global address may be per-lane (scatter OK);
// LDS side is wave-uniform base + lane*16B.
__device__ __forceinline__ void ld_lds16(const u16* g, u16* l) {
    __builtin_amdgcn_global_load_lds(
        (__attribute__((address_space(1))) void*)(uintptr_t)(const void*)g,
        (__attribute__((address_space(3))) void*)l, 16, 0, 0);
}

// ---------------------------------------------------------------------------
// prep_k: one dispatch, grid-partitioned 3136 blocks of 256 threads.
//   [0,2048)    : transpose emb1->emb1t, emb2->emb2t (f32 -> bf16, stride 512)
//   [2048,2880) : weight pack f32->bf16 into wp (stacked [r|t] per layer)
//   [2880,3136) : 1-NN, atomicMin on (d2bits<<32|idx) keys
// ---------------------------------------------------------------------------
__global__ __launch_bounds__(256) void prep_k(
    const float* __restrict__ emb1, const float* __restrict__ emb2,
    const float* __restrict__ t1,   const float* __restrict__ t2,
    const float* __restrict__ w1r, const float* __restrict__ w1t,
    const float* __restrict__ w2r, const float* __restrict__ w2t,
    const float* __restrict__ w3r, const float* __restrict__ w3t,
    u16* __restrict__ e1t, u16* __restrict__ e2t, u16* __restrict__ wp,
    unsigned long long* __restrict__ keys)
{
    __shared__ __align__(16) char smem[64 * 66 * 4];
    const int bid = blockIdx.x;
    const int t = threadIdx.x;

    if (bid < 2048) {                                  // ---- transpose ----
        float (*tile)[66] = (float(*)[66])smem;
        const int z = bid >> 10, rem = bid & 1023;
        const float* in = z ? emb2 : emb1;
        u16* out = z ? e2t : e1t;
        const int n0 = (rem & 127) * 64, f0 = (rem >> 7) * 64;
        const int c = t & 63, r4 = t >> 6;
#pragma unroll
        for (int p = 0; p < 16; ++p) {
            int fr = p * 4 + r4;
            tile[fr][c] = in[(size_t)(f0 + fr) * 8192 + n0 + c];
        }
        __syncthreads();
#pragma unroll
        for (int p = 0; p < 16; ++p) {
            int nr = p * 4 + r4;
            out[(size_t)(n0 + nr) * 512 + f0 + c] = f2b(tile[c][nr]);
        }
    } else if (bid < 2880) {                           // ---- weight pack ----
        size_t i = (size_t)(bid - 2048) * 2048 + (size_t)t * 8;
        const float* src; size_t off;
        if (i < 655360)       { src = w1r; off = 0; }
        else if (i < 1310720) { src = w1t; off = 655360; }
        else if (i < 1474560) { src = w2r; off = 1310720; }
        else if (i < 1638400) { src = w2t; off = 1474560; }
        else if (i < 1671168) { src = w3r; off = 1638400; }
        else                  { src = w3t; off = 1671168; }
        const float4 lo = *(const float4*)(src + (i - off));
        const float4 hi = *(const float4*)(src + (i - off) + 4);
        ushort4 o0, o1;
        o0.x = f2b(lo.x); o0.y = f2b(lo.y); o0.z = f2b(lo.z); o0.w = f2b(lo.w);
        o1.x = f2b(hi.x); o1.y = f2b(hi.y); o1.z = f2b(hi.z); o1.w = f2b(hi.w);
        *(ushort4*)(wp + i) = o0;
        *(ushort4*)(wp + i + 4) = o1;
    } else {                                           // ---- 1-NN ----
        float4* ref = (float4*)smem;
        const int kid = bid - 2880;
        const int rs = kid & 63, qb = kid >> 6;
        if (t < 128) {
            int i = rs * 128 + t;
            float x = t1[i], y = t1[8192 + i], z = t1[16384 + i];
            float rr = __fadd_rn(__fadd_rn(__fmul_rn(x, x), __fmul_rn(y, y)),
                                 __fmul_rn(z, z));
            ref[t] = make_float4(x, y, z, rr);
        }
        __syncthreads();
        float qx[8], qy[8], qz[8], qq[8], bestd[8];
        int besti[8];
        const int q0 = qb * 2048 + t;
#pragma unroll
        for (int j = 0; j < 8; ++j) {
            int q = q0 + j * 256;
            qx[j] = t2[q]; qy[j] = t2[8192 + q]; qz[j] = t2[16384 + q];
            qq[j] = __fadd_rn(__fadd_rn(__fmul_rn(qx[j], qx[j]),
                                        __fmul_rn(qy[j], qy[j])),
                              __fmul_rn(qz[j], qz[j]));
            bestd[j] = __uint_as_float(0x7f800000u);
            besti[j] = 0;
        }
        for (int i = 0; i < 128; ++i) {
            float4 r = ref[i];
            int ridx = rs * 128 + i;
#pragma unroll
            for (int j = 0; j < 8; ++j) {
                float g = __fmaf_rn(qz[j], r.z,
                          __fmaf_rn(qy[j], r.y, __fmul_rn(qx[j], r.x)));
                float d2 = __fsub_rn(__fadd_rn(r.w, qq[j]), __fmul_rn(2.0f, g));
                if (d2 < bestd[j]) { bestd[j] = d2; besti[j] = ridx; }
            }
        }
#pragma unroll
        for (int j = 0; j < 8; ++j) {
            unsigned long long key =
                ((unsigned long long)__float_as_uint(bestd[j]) << 32) |
                (unsigned int)besti[j];
            atomicMin(&keys[q0 + j * 256], key);
        }
    }
}

// ---------------------------------------------------------------------------
// gemm1: h1t[n][m] = relu( sum_k A[m][k] * B[n][k] + bias[m] )
// A: bf16 1280x1024 stacked [w1r|w1t]. B row n: k 0..511 = emb1t[idx[n]],
// k 512..1023 = emb2t[n] — gather folded into B-staging via per-lane
// global_load_lds addresses. 128x128 tile, BK=32, m97 structure.
// ---------------------------------------------------------------------------
__global__ __launch_bounds__(256) void gemm1_k(
    const u16* __restrict__ A,
    const float* __restrict__ b1r, const float* __restrict__ b1t,
    const unsigned long long* __restrict__ keys,
    const u16* __restrict__ e1t, const u16* __restrict__ e2t,
    u16* __restrict__ Ct)
{
    __shared__ __align__(16) u16 lds_a[128 * 32];
    __shared__ __align__(16) u16 lds_b[128 * 32];

    const int t = threadIdx.x;
    const int n0 = blockIdx.x * 128;
    const int m0 = blockIdx.y * 128;
    const int w = t >> 6, l = t & 63;
    const int sr = l >> 2, sc = (l & 3) * 8;

    const u16* gA0 = A + (size_t)(m0 + w * 32 + sr) * 1024 + sc;
    const u16* gA1 = gA0 + (size_t)16 * 1024;
    u16* lA0 = &lds_a[w * 1024];
    u16* lA1 = lA0 + 512;

    const int r0 = n0 + w * 32 + sr, r1 = r0 + 16;
    const int i0 = (int)(keys[r0] & 0xffffffffu);
    const int i1 = (int)(keys[r1] & 0xffffffffu);
    const u16* pI0 = e1t + (size_t)i0 * 512 + sc;   // indirect half (k<512)
    const u16* pI1 = e1t + (size_t)i1 * 512 + sc;
    const u16* pD0 = e2t + (size_t)r0 * 512 + sc;   // direct half (k>=512)
    const u16* pD1 = e2t + (size_t)r1 * 512 + sc;
    u16* lB0 = &lds_b[w * 1024];
    u16* lB1 = lB0 + 512;

    const int wm = (w & 1) * 64;
    const int wn = (w >> 1) * 64;
    const int lrow = l & 15, quad = l >> 4;
    const u16* fa = &lds_a[(wm + lrow) * 32 + quad * 8];
    const u16* fb = &lds_b[(wn + lrow) * 32 + quad * 8];

    f32x4 acc[4][4];
#pragma unroll
    for (int i = 0; i < 4; ++i)
#pragma unroll
        for (int j = 0; j < 4; ++j)
            acc[i][j] = (f32x4){0.f, 0.f, 0.f, 0.f};

    ld_lds16(gA0, lA0); ld_lds16(gA1, lA1);
    ld_lds16(pI0, lB0); ld_lds16(pI1, lB1);

    for (int kt = 0; kt < 1024; kt += 32) {
        __syncthreads();
        bf16x8 af[4], bfr[4];
#pragma unroll
        for (int i = 0; i < 4; ++i) af[i] = *(const bf16x8*)(fa + i * 16 * 32);
#pragma unroll
        for (int j = 0; j < 4; ++j) bfr[j] = *(const bf16x8*)(fb + j * 16 * 32);
        __syncthreads();
        const int kn = kt + 32;
        if (kn < 1024) {
            gA0 += 32; gA1 += 32;
            const u16* s0 = (kn < 512) ? pI0 + kn : pD0 + (kn - 512);
            const u16* s1 = (kn < 512) ? pI1 + kn : pD1 + (kn - 512);
            ld_lds16(gA0, lA0); ld_lds16(gA1, lA1);
            ld_lds16(s0, lB0); ld_lds16(s1, lB1);
        }
#pragma unroll
        for (int i = 0; i < 4; ++i)
#pragma unroll
            for (int j = 0; j < 4; ++j)
                acc[i][j] = __builtin_amdgcn_mfma_f32_16x16x32_bf16(
                    af[i], bfr[j], acc[i][j], 0, 0, 0);
    }

    const float* bias = (m0 < 640) ? b1r : b1t;
    const int boff = (m0 < 640) ? 0 : 640;
#pragma unroll
    for (int i = 0; i < 4; ++i) {
        const int mbase = m0 + wm + i * 16 + quad * 4;
        const float4 bbv = *(const float4*)&bias[mbase - boff];
#pragma unroll
        for (int j = 0; j < 4; ++j) {
            const int n = n0 + wn + j * 16 + lrow;
            f32x4 v = acc[i][j];
            float x0 = fmaxf(v[0] + bbv.x, 0.f), x1 = fmaxf(v[1] + bbv.y, 0.f);
            float x2 = fmaxf(v[2] + bbv.z, 0.f), x3 = fmaxf(v[3] + bbv.w, 0.f);
            ushort4 o;
            o.x = f2b(x0); o.y = f2b(x1); o.z = f2b(x2); o.w = f2b(x3);
            *(ushort4*)&Ct[(size_t)n * 1280 + mbase] = o;
        }
    }
}

// ---------------------------------------------------------------------------
// gemm_bt (layers 2/3): A stacked [r|t] (2*Mb x K) bf16; branch by m0 vs Mb.
// Ct[n][mbase] = relu( sum_k A[mbase][k]*Bt[n][br*b_step+k] + bias ).
// 128m x 64n tile, BK=32, m97 staging.
// ---------------------------------------------------------------------------
__global__ __launch_bounds__(256) void gemm_bt(
    const u16* __restrict__ A,
    const float* __restrict__ biasr, const float* __restrict__ biast,
    const u16* __restrict__ Bt, u16* __restrict__ Ct,
    int Mb, int K, int bstride, int b_step, int ostride)
{
    __shared__ __align__(16) u16 lds_a[128 * 32];
    __shared__ __align__(16) u16 lds_b[64 * 32];

    const int t = threadIdx.x;
    const int n0 = blockIdx.x * 64;
    const int m0 = blockIdx.y * 128;
    const int br = (m0 >= Mb);

    const int w = t >> 6, l = t & 63;
    const int sr = l >> 2, sc = (l & 3) * 8;

    const u16* gA0 = A + (size_t)(m0 + w * 32 + sr) * K + sc;
    const u16* gA1 = gA0 + (size_t)16 * K;
    u16* lA0 = &lds_a[w * 1024];
    u16* lA1 = lA0 + 512;

    const u16* gB0 = Bt + (size_t)(n0 + w * 16 + sr) * bstride + br * b_step + sc;
    u16* lB0 = &lds_b[w * 512];

    const int wm = (w & 1) * 64;
    const int wn = (w >> 1) * 32;
    const int lrow = l & 15, quad = l >> 4;
    const u16* fa = &lds_a[(wm + lrow) * 32 + quad * 8];
    const u16* fb = &lds_b[(wn + lrow) * 32 + quad * 8];

    f32x4 acc[4][2];
#pragma unroll
    for (int i = 0; i < 4; ++i)
#pragma unroll
        for (int j = 0; j < 2; ++j)
            acc[i][j] = (f32x4){0.f, 0.f, 0.f, 0.f};

    ld_lds16(gA0, lA0); ld_lds16(gA1, lA1);
    ld_lds16(gB0, lB0);

    for (int kt = 0; kt < K; kt += 32) {
        __syncthreads();
        bf16x8 af[4], bfr[2];
#pragma unroll
        for (int i = 0; i < 4; ++i) af[i] = *(const bf16x8*)(fa + i * 16 * 32);
#pragma unroll
        for (int j = 0; j < 2; ++j) bfr[j] = *(const bf16x8*)(fb + j * 16 * 32);
        __syncthreads();
        if (kt + 32 < K) {
            gA0 += 32; gA1 += 32; gB0 += 32;
            ld_lds16(gA0, lA0); ld_lds16(gA1, lA1);
            ld_lds16(gB0, lB0);
        }
#pragma unroll
        for (int i = 0; i < 4; ++i)
#pragma unroll
            for (int j = 0; j < 2; ++j)
                acc[i][j] = __builtin_amdgcn_mfma_f32_16x16x32_bf16(
                    af[i], bfr[j], acc[i][j], 0, 0, 0);
    }

    const float* bias = br ? biast : biasr;
    const int boff = br * Mb;
#pragma unroll
    for (int i = 0; i < 4; ++i) {
        const int mbase = m0 + wm + i * 16 + quad * 4;
        const float4 bbv = *(const float4*)&bias[mbase - boff];
#pragma unroll
        for (int j = 0; j < 2; ++j) {
            const int n = n0 + wn + j * 16 + lrow;
            f32x4 v = acc[i][j];
            float x0 = fmaxf(v[0] + bbv.x, 0.f), x1 = fmaxf(v[1] + bbv.y, 0.f);
            float x2 = fmaxf(v[2] + bbv.z, 0.f), x3 = fmaxf(v[3] + bbv.w, 0.f);
            ushort4 o;
            o.x = f2b(x0); o.y = f2b(x1); o.z = f2b(x2); o.w = f2b(x3);
            *(ushort4*)&Ct[(size_t)n * ostride + mbase] = o;
        }
    }
}

// ---------------------------------------------------------------------------
// Layer 4 (obj-sliced, f32 weights) + transpose + concat, f32 output.
// ---------------------------------------------------------------------------
__global__ void final_k(const u16* __restrict__ h3t,
                        const float* __restrict__ w4r, const float* __restrict__ b4r,
                        const float* __restrict__ w4t, const float* __restrict__ b4t,
                        const int* __restrict__ objp, float* __restrict__ out)
{
    __shared__ float wr[4 * 128], wt[3 * 128], bb[7];
    const int t = threadIdx.x;
    const int o = objp[0];
    if (t < 128) {
#pragma unroll
        for (int r = 0; r < 4; ++r) wr[r * 128 + t] = w4r[(o * 4 + r) * 128 + t];
#pragma unroll
        for (int r = 0; r < 3; ++r) wt[r * 128 + t] = w4t[(o * 3 + r) * 128 + t];
    } else if (t < 135) {
        int r = t - 128;
        bb[r] = (r < 4) ? b4r[o * 4 + r] : b4t[o * 3 + (r - 4)];
    }
    __syncthreads();

    const int n = blockIdx.x * 256 + t;
    const u16* hp = h3t + (size_t)n * 256;
    float ar0 = 0, ar1 = 0, ar2 = 0, ar3 = 0, at0 = 0, at1 = 0, at2 = 0;
#pragma unroll
    for (int k = 0; k < 128; k += 8) {
        uint4 hv = *(const uint4*)(hp + k);
        const u16* hs = (const u16*)&hv;
        uint4 gv = *(const uint4*)(hp + 128 + k);
        const u16* gs = (const u16*)&gv;
#pragma unroll
        for (int j = 0; j < 8; ++j) {
            float h = b2f(hs[j]);
            ar0 = fmaf(h, wr[k + j], ar0);
            ar1 = fmaf(h, wr[128 + k + j], ar1);
            ar2 = fmaf(h, wr[256 + k + j], ar2);
            ar3 = fmaf(h, wr[384 + k + j], ar3);
            float g = b2f(gs[j]);
            at0 = fmaf(g, wt[k + j], at0);
            at1 = fmaf(g, wt[128 + k + j], at1);
            at2 = fmaf(g, wt[256 + k + j], at2);
        }
    }
    float4 ro = make_float4(ar0 + bb[0], ar1 + bb[1], ar2 + bb[2], ar3 + bb[3]);
    *(float4*)&out[n * 4] = ro;
    float* tp = out + 32768 + n * 3;
    tp[0] = at0 + bb[4]; tp[1] = at1 + bb[5]; tp[2] = at2 + bb[6];
}

// ---------------------------------------------------------------------------
extern "C" void kernel_launch(void* const* d_in, const int* in_sizes, int n_in,
                              void* d_out, int out_size, void* d_ws, size_t ws_size,
                              hipStream_t stream)
{
    const float* emb1 = (const float*)d_in[0];
    const float* emb2 = (const float*)d_in[1];
    const float* t1   = (const float*)d_in[2];
    const float* t2   = (const float*)d_in[3];
    const int*   obj  = (const int*)d_in[4];
    const float* w1r = (const float*)d_in[5];  const float* b1r = (const float*)d_in[6];
    const float* w2r = (const float*)d_in[7];  const float* b2r = (const float*)d_in[8];
    const float* w3r = (const float*)d_in[9];  const float* b3r = (const float*)d_in[10];
    const float* w4r = (const float*)d_in[11]; const float* b4r = (const float*)d_in[12];
    const float* w1t = (const float*)d_in[13]; const float* b1t = (const float*)d_in[14];
    const float* w2t = (const float*)d_in[15]; const float* b2t = (const float*)d_in[16];
    const float* w3t = (const float*)d_in[17]; const float* b3t = (const float*)d_in[18];
    const float* w4t = (const float*)d_in[19]; const float* b4t = (const float*)d_in[20];

    char* ws = (char*)d_ws;
    unsigned long long* keys = (unsigned long long*)ws;            // 64 KB
    u16* e1t = (u16*)(ws + (1u << 16));                            // 8 MB (8192x512)
    u16* e2t = (u16*)(ws + (1u << 16) + (8u << 20));               // 8 MB (8192x512)
    u16* h1t = (u16*)(ws + (1u << 16) + (16u << 20));              // 20 MB (8192x1280)
    u16* h2t = (u16*)(ws + (1u << 16) + (36u << 20));              // 8 MB (8192x512)
    u16* h3t = (u16*)(ws + (1u << 16) + (44u << 20));              // 4 MB (8192x256)
    u16* wp  = (u16*)(ws + (1u << 16) + (48u << 20));              // 3.25 MB

    u16* w1p = wp;             // 1280x1024 = [w1r|w1t]
    u16* w2p = wp + 1310720;   // 512x640  = [w2r|w2t]
    u16* w3p = wp + 1638400;   // 256x256  = [w3r|w3t]

    hipMemsetAsync(keys, 0xFF, 8192 * sizeof(unsigned long long), stream);
    prep_k<<<3136, 256, 0, stream>>>(emb1, emb2, t1, t2,
                                     w1r, w1t, w2r, w2t, w3r, w3t,
                                     e1t, e2t, wp, keys);
    gemm1_k<<<dim3(64, 10), 256, 0, stream>>>(w1p, b1r, b1t, keys, e1t, e2t, h1t);
    gemm_bt<<<dim3(128, 4), 256, 0, stream>>>(w2p, b2r, b2t, h1t, h2t, 256, 640, 1280, 640, 512);
    gemm_bt<<<dim3(128, 2), 256, 0, stream>>>(w3p, b3r, b3t, h2t, h3t, 128, 256, 512, 256, 256);
    final_k<<<32, 256, 0, stream>>>(h3t, w4r, b4r, w4t, b4t, obj, (float*)d_out);
}

// Round 6
// 210.914 us; speedup vs baseline: 1.0614x; 1.0614x over previous
//
#include <hip/hip_runtime.h>

typedef unsigned short u16;
typedef __bf16 bf16x8 __attribute__((ext_vector_type(8)));
typedef float f32x4 __attribute__((ext_vector_type(4)));

__device__ __forceinline__ float b2f(u16 v) {
    return __uint_as_float(((unsigned int)v) << 16);
}
__device__ __forceinline__ u16 f2b(float f) {
    unsigned int u = __float_as_uint(f);
    u += 0x7fffu + ((u >> 16) & 1u);   // RNE
    return (u16)(u >> 16);
}

// async global->LDS, 16B per lane; LDS dest is wave-uniform base + lane*16B.
__device__ __forceinline__ void ld_lds16(const u16* g, u16* l) {
    __builtin_amdgcn_global_load_lds(
        (__attribute__((address_space(1))) void*)(uintptr_t)(const void*)g,
        (__attribute__((address_space(3))) void*)l, 16, 0, 0);
}

// ---------------------------------------------------------------------------
// Weight pre-pack: f32 -> bf16, segments laid out contiguously in ws.
// [w1r 655360 | w1t 655360 | w2r 163840 | w2t 163840 | w3r 32768 | w3t 32768]
// ---------------------------------------------------------------------------
__global__ void pack_w_k(const float* __restrict__ w1r, const float* __restrict__ w1t,
                         const float* __restrict__ w2r, const float* __restrict__ w2t,
                         const float* __restrict__ w3r, const float* __restrict__ w3t,
                         u16* __restrict__ dst)
{
    size_t i = (size_t)blockIdx.x * 2048 + (size_t)threadIdx.x * 8;
    const float* src; size_t off;
    if (i < 655360)       { src = w1r; off = 0; }
    else if (i < 1310720) { src = w1t; off = 655360; }
    else if (i < 1474560) { src = w2r; off = 1310720; }
    else if (i < 1638400) { src = w2t; off = 1474560; }
    else if (i < 1671168) { src = w3r; off = 1638400; }
    else                  { src = w3t; off = 1671168; }
    const float4 lo = *(const float4*)(src + (i - off));
    const float4 hi = *(const float4*)(src + (i - off) + 4);
    ushort4 o0, o1;
    o0.x = f2b(lo.x); o0.y = f2b(lo.y); o0.z = f2b(lo.z); o0.w = f2b(lo.w);
    o1.x = f2b(hi.x); o1.y = f2b(hi.y); o1.z = f2b(hi.z); o1.w = f2b(hi.w);
    *(ushort4*)(dst + i) = o0;
    *(ushort4*)(dst + i + 4) = o1;
}

// ---------------------------------------------------------------------------
// 1-NN (f32, mimics np: d2 = rr[i] + qq[j] - 2*g), atomicMin on (d2||idx) key.
// ---------------------------------------------------------------------------
__global__ void knn_k(const float* __restrict__ t1, const float* __restrict__ t2,
                      unsigned long long* __restrict__ keys)
{
    __shared__ float4 ref[128];   // x,y,z,rr
    const int t = threadIdx.x;
    const int rs = blockIdx.x;
    const int qb = blockIdx.y;
    if (t < 128) {
        int i = rs * 128 + t;
        float x = t1[i], y = t1[8192 + i], z = t1[16384 + i];
        float rr = __fadd_rn(__fadd_rn(__fmul_rn(x, x), __fmul_rn(y, y)), __fmul_rn(z, z));
        ref[t] = make_float4(x, y, z, rr);
    }
    __syncthreads();

    float qx[8], qy[8], qz[8], qq[8], bestd[8];
    int besti[8];
    const int q0 = qb * 2048 + t;
#pragma unroll
    for (int j = 0; j < 8; ++j) {
        int q = q0 + j * 256;
        qx[j] = t2[q]; qy[j] = t2[8192 + q]; qz[j] = t2[16384 + q];
        qq[j] = __fadd_rn(__fadd_rn(__fmul_rn(qx[j], qx[j]), __fmul_rn(qy[j], qy[j])),
                          __fmul_rn(qz[j], qz[j]));
        bestd[j] = __uint_as_float(0x7f800000u);
        besti[j] = 0;
    }
    for (int i = 0; i < 128; ++i) {
        float4 r = ref[i];
        int ridx = rs * 128 + i;
#pragma unroll
        for (int j = 0; j < 8; ++j) {
            float g = __fmaf_rn(qz[j], r.z, __fmaf_rn(qy[j], r.y, __fmul_rn(qx[j], r.x)));
            float d2 = __fsub_rn(__fadd_rn(r.w, qq[j]), __fmul_rn(2.0f, g));
            if (d2 < bestd[j]) { bestd[j] = d2; besti[j] = ridx; }
        }
    }
#pragma unroll
    for (int j = 0; j < 8; ++j) {
        unsigned long long key =
            ((unsigned long long)__float_as_uint(bestd[j]) << 32) | (unsigned int)besti[j];
        atomicMin(&keys[q0 + j * 256], key);
    }
}

// ---------------------------------------------------------------------------
// Both transposes in one dispatch: z=0 emb1->emb1t(512), z=1 emb2->Xt cols 512+.
// [64][65] tile: conflict-free LDS (2-way only, free). Store phase: ushort4
// per lane (4 rows x 64 f per wave-instruction, 128B segments).
// ---------------------------------------------------------------------------
__global__ void transpose_k(const float* __restrict__ e1, const float* __restrict__ e2,
                            u16* __restrict__ o1, u16* __restrict__ o2)
{
    __shared__ float tile[64][65];
    const float* in = blockIdx.z ? e2 : e1;
    u16* out = blockIdx.z ? o2 : o1;
    const int ostride = blockIdx.z ? 1024 : 512;
    const int coff = blockIdx.z ? 512 : 0;
    const int t = threadIdx.x;
    const int n0 = blockIdx.x * 64, f0 = blockIdx.y * 64;
    const int c = t & 63, r4 = t >> 6;
#pragma unroll
    for (int p = 0; p < 16; ++p) {
        int fr = p * 4 + r4;
        tile[fr][c] = in[(size_t)(f0 + fr) * 8192 + n0 + c];
    }
    __syncthreads();
    const int fc = (t & 15) * 4;    // f-chunk of 4
    const int nr4 = t >> 4;         // 16 n-rows covered per pass
#pragma unroll
    for (int p = 0; p < 4; ++p) {
        int nr = p * 16 + nr4;
        ushort4 o;
        o.x = f2b(tile[fc + 0][nr]); o.y = f2b(tile[fc + 1][nr]);
        o.z = f2b(tile[fc + 2][nr]); o.w = f2b(tile[fc + 3][nr]);
        *(ushort4*)&out[(size_t)(n0 + nr) * ostride + coff + f0 + fc] = o;
    }
}

// ---------------------------------------------------------------------------
// Gather: Xt[n][0:512] = emb1t[idx[n]][0:512]. One wave per row (1KB).
// ---------------------------------------------------------------------------
__global__ void gather_k(const unsigned long long* __restrict__ keys,
                         const u16* __restrict__ emb1t, u16* __restrict__ Xt)
{
    const int t = threadIdx.x, w = t >> 6, l = t & 63;
    const int nbase = blockIdx.x * 32;
#pragma unroll
    for (int it = 0; it < 8; ++it) {
        int n = nbase + it * 4 + w;
        int i = (int)(keys[n] & 0xffffffffu);
        const uint4* src = (const uint4*)(emb1t + (size_t)i * 512);
        uint4* dst = (uint4*)(Xt + (size_t)n * 1024);
        dst[l] = src[l];
    }
}

// ---------------------------------------------------------------------------
// GEMM (BT): Ct[n][out_off+m] = act( sum_k A[m][k]*Bt[n][b_off+k] + bias[m] )
// A: bf16 (Mh x K) row-major (pre-packed). Bt: bf16 (8192 x bstride).
// 128m x TNn tile, BK=32, global_load_lds staging (m97 structure).
// Wave grid 2x2: wm = (w&1)*64, wn = (w>>1)*(TN/2).
// ---------------------------------------------------------------------------
template <int TN>
__global__ __launch_bounds__(256) void gemm_bt(
    const u16* __restrict__ Ar, const u16* __restrict__ At,
    const float* __restrict__ biasr, const float* __restrict__ biast,
    const u16* __restrict__ Bt, u16* __restrict__ Ct,
    int Mh, int K, int bstride, int b_step, int ostride, int relu)
{
    constexpr int NJ = TN / 32;               // 4 or 2
    __shared__ __align__(16) u16 lds_a[128 * 32];
    __shared__ __align__(16) u16 lds_b[TN * 32];

    const int t = threadIdx.x;
    const int n0 = blockIdx.x * TN;
    const int m0 = blockIdx.y * 128;
    const int branch = blockIdx.z;

    const u16* A = branch ? At : Ar;
    const float* bias = branch ? biast : biasr;
    const int b_off = branch * b_step;
    const int out_off = branch * Mh;

    const int w = t >> 6, l = t & 63;
    const int sr = l >> 2, sc = (l & 3) * 8;   // staging: row-in-16, k-chunk

    // A staging: wave w covers rows w*32 .. w*32+31 (two 16-row issues)
    const u16* gA0 = A + (size_t)(m0 + w * 32 + sr) * K + sc;
    const u16* gA1 = gA0 + (size_t)16 * K;
    u16* lA0 = &lds_a[w * 1024];
    u16* lA1 = lA0 + 512;

    // B staging
    const u16* gB0;
    const u16* gB1 = nullptr;
    u16 *lB0, *lB1 = nullptr;
    if (TN == 128) {
        gB0 = Bt + (size_t)(n0 + w * 32 + sr) * bstride + b_off + sc;
        gB1 = gB0 + (size_t)16 * bstride;
        lB0 = &lds_b[w * 1024];
        lB1 = lB0 + 512;
    } else {  // TN == 64: wave w covers rows w*16 .. w*16+15 (one issue)
        gB0 = Bt + (size_t)(n0 + w * 16 + sr) * bstride + b_off + sc;
        lB0 = &lds_b[w * 512];
    }

    const int wm = (w & 1) * 64;
    const int wn = (w >> 1) * (TN / 2);       // 64 or 32
    const int lrow = l & 15, quad = l >> 4;
    const u16* fa = &lds_a[(wm + lrow) * 32 + quad * 8];
    const u16* fb = &lds_b[(wn + lrow) * 32 + quad * 8];

    f32x4 acc[4][NJ];
#pragma unroll
    for (int i = 0; i < 4; ++i)
#pragma unroll
        for (int j = 0; j < NJ; ++j)
            acc[i][j] = (f32x4){0.f, 0.f, 0.f, 0.f};

    // prologue: issue tile 0
    ld_lds16(gA0, lA0); ld_lds16(gA1, lA1);
    ld_lds16(gB0, lB0);
    if (TN == 128) ld_lds16(gB1, lB1);

    for (int kt = 0; kt < K; kt += 32) {
        __syncthreads();                       // vmcnt(0) drain: tile ready
        bf16x8 af[4], bfr[NJ];
#pragma unroll
        for (int i = 0; i < 4; ++i) af[i] = *(const bf16x8*)(fa + i * 16 * 32);
#pragma unroll
        for (int j = 0; j < NJ; ++j) bfr[j] = *(const bf16x8*)(fb + j * 16 * 32);
        __syncthreads();                       // frags in regs: LDS reusable
        if (kt + 32 < K) {                     // issue next tile; overlaps MFMA
            gA0 += 32; gA1 += 32; gB0 += 32;
            ld_lds16(gA0, lA0); ld_lds16(gA1, lA1);
            ld_lds16(gB0, lB0);
            if (TN == 128) { gB1 += 32; ld_lds16(gB1, lB1); }
        }
#pragma unroll
        for (int i = 0; i < 4; ++i)
#pragma unroll
            for (int j = 0; j < NJ; ++j)
                acc[i][j] = __builtin_amdgcn_mfma_f32_16x16x32_bf16(
                    af[i], bfr[j], acc[i][j], 0, 0, 0);
    }

    // epilogue: D row m = quad*4+reg, col n = lrow
#pragma unroll
    for (int i = 0; i < 4; ++i) {
        const int mbase = m0 + wm + i * 16 + quad * 4;
        const float4 bbv = *(const float4*)&bias[mbase];
#pragma unroll
        for (int j = 0; j < NJ; ++j) {
            const int n = n0 + wn + j * 16 + lrow;
            f32x4 v = acc[i][j];
            float x0 = v[0] + bbv.x, x1 = v[1] + bbv.y;
            float x2 = v[2] + bbv.z, x3 = v[3] + bbv.w;
            if (relu) {
                x0 = fmaxf(x0, 0.f); x1 = fmaxf(x1, 0.f);
                x2 = fmaxf(x2, 0.f); x3 = fmaxf(x3, 0.f);
            }
            ushort4 o;
            o.x = f2b(x0); o.y = f2b(x1); o.z = f2b(x2); o.w = f2b(x3);
            *(ushort4*)&Ct[(size_t)n * ostride + out_off + mbase] = o;
        }
    }
}

// ---------------------------------------------------------------------------
// Layer 4 (obj-sliced, f32 weights) + transpose + concat, f32 output.
// ---------------------------------------------------------------------------
__global__ void final_k(const u16* __restrict__ h3t,
                        const float* __restrict__ w4r, const float* __restrict__ b4r,
                        const float* __restrict__ w4t, const float* __restrict__ b4t,
                        const int* __restrict__ objp, float* __restrict__ out)
{
    __shared__ float wr[4 * 128], wt[3 * 128], bb[7];
    const int t = threadIdx.x;
    const int o = objp[0];
    if (t < 128) {
#pragma unroll
        for (int r = 0; r < 4; ++r) wr[r * 128 + t] = w4r[(o * 4 + r) * 128 + t];
#pragma unroll
        for (int r = 0; r < 3; ++r) wt[r * 128 + t] = w4t[(o * 3 + r) * 128 + t];
    } else if (t < 135) {
        int r = t - 128;
        bb[r] = (r < 4) ? b4r[o * 4 + r] : b4t[o * 3 + (r - 4)];
    }
    __syncthreads();

    const int n = blockIdx.x * 256 + t;
    const u16* hp = h3t + (size_t)n * 256;
    float ar0 = 0, ar1 = 0, ar2 = 0, ar3 = 0, at0 = 0, at1 = 0, at2 = 0;
#pragma unroll
    for (int k = 0; k < 128; k += 8) {
        uint4 hv = *(const uint4*)(hp + k);
        const u16* hs = (const u16*)&hv;
        uint4 gv = *(const uint4*)(hp + 128 + k);
        const u16* gs = (const u16*)&gv;
#pragma unroll
        for (int j = 0; j < 8; ++j) {
            float h = b2f(hs[j]);
            ar0 = fmaf(h, wr[k + j], ar0);
            ar1 = fmaf(h, wr[128 + k + j], ar1);
            ar2 = fmaf(h, wr[256 + k + j], ar2);
            ar3 = fmaf(h, wr[384 + k + j], ar3);
            float g = b2f(gs[j]);
            at0 = fmaf(g, wt[k + j], at0);
            at1 = fmaf(g, wt[128 + k + j], at1);
            at2 = fmaf(g, wt[256 + k + j], at2);
        }
    }
    float4 ro = make_float4(ar0 + bb[0], ar1 + bb[1], ar2 + bb[2], ar3 + bb[3]);
    *(float4*)&out[n * 4] = ro;
    float* tp = out + 32768 + n * 3;
    tp[0] = at0 + bb[4]; tp[1] = at1 + bb[5]; tp[2] = at2 + bb[6];
}

// ---------------------------------------------------------------------------
extern "C" void kernel_launch(void* const* d_in, const int* in_sizes, int n_in,
                              void* d_out, int out_size, void* d_ws, size_t ws_size,
                              hipStream_t stream)
{
    const float* emb1 = (const float*)d_in[0];
    const float* emb2 = (const float*)d_in[1];
    const float* t1   = (const float*)d_in[2];
    const float* t2   = (const float*)d_in[3];
    const int*   obj  = (const int*)d_in[4];
    const float* w1r = (const float*)d_in[5];  const float* b1r = (const float*)d_in[6];
    const float* w2r = (const float*)d_in[7];  const float* b2r = (const float*)d_in[8];
    const float* w3r = (const float*)d_in[9];  const float* b3r = (const float*)d_in[10];
    const float* w4r = (const float*)d_in[11]; const float* b4r = (const float*)d_in[12];
    const float* w1t = (const float*)d_in[13]; const float* b1t = (const float*)d_in[14];
    const float* w2t = (const float*)d_in[15]; const float* b2t = (const float*)d_in[16];
    const float* w3t = (const float*)d_in[17]; const float* b3t = (const float*)d_in[18];
    const float* w4t = (const float*)d_in[19]; const float* b4t = (const float*)d_in[20];

    char* ws = (char*)d_ws;
    unsigned long long* keys = (unsigned long long*)ws;          // 64 KB
    u16* emb1t = (u16*)(ws + (1u << 16));                        // 8 MB  (8192x512)
    u16* Xt    = (u16*)(ws + (1u << 16) + (8u << 20));           // 16 MB (8192x1024)
    u16* h1t   = (u16*)(ws + (1u << 16) + (24u << 20));          // 20 MB (8192x1280)
    u16* wp    = (u16*)(ws + (1u << 16) + (44u << 20));          // 3.25 MB packed weights
    u16* h2t   = emb1t;   // reuse after gather
    u16* h3t   = Xt;      // reuse after layer 1

    u16* w1rp = wp;            u16* w1tp = wp + 655360;
    u16* w2rp = wp + 1310720;  u16* w2tp = wp + 1474560;
    u16* w3rp = wp + 1638400;  u16* w3tp = wp + 1671168;

    hipMemsetAsync(keys, 0xFF, 8192 * sizeof(unsigned long long), stream);
    pack_w_k<<<832, 256, 0, stream>>>(w1r, w1t, w2r, w2t, w3r, w3t, wp);
    knn_k<<<dim3(64, 4), 256, 0, stream>>>(t1, t2, keys);
    transpose_k<<<dim3(128, 8, 2), 256, 0, stream>>>(emb1, emb2, emb1t, Xt);
    gather_k<<<256, 256, 0, stream>>>(keys, emb1t, Xt);
    gemm_bt<128><<<dim3(64, 5, 2), 256, 0, stream>>>(w1rp, w1tp, b1r, b1t, Xt,  h1t, 640, 1024, 1024,   0, 1280, 1);
    gemm_bt<64><<<dim3(128, 2, 2), 256, 0, stream>>>(w2rp, w2tp, b2r, b2t, h1t, h2t, 256,  640, 1280, 640,  512, 1);
    gemm_bt<64><<<dim3(128, 1, 2), 256, 0, stream>>>(w3rp, w3tp, b3r, b3t, h2t, h3t, 128,  256,  512, 256,  256, 1);
    final_k<<<32, 256, 0, stream>>>(h3t, w4r, b4r, w4t, b4t, obj, (float*)d_out);
}

// Round 7
// 198.845 us; speedup vs baseline: 1.1258x; 1.0607x over previous
//
#include <hip/hip_runtime.h>

typedef unsigned short u16;
typedef __bf16 bf16x8 __attribute__((ext_vector_type(8)));
typedef float f32x4 __attribute__((ext_vector_type(4)));

__device__ __forceinline__ float b2f(u16 v) {
    return __uint_as_float(((unsigned int)v) << 16);
}
__device__ __forceinline__ u16 f2b(float f) {
    unsigned int u = __float_as_uint(f);
    u += 0x7fffu + ((u >> 16) & 1u);   // RNE
    return (u16)(u >> 16);
}

// async global->LDS, 16B per lane; LDS dest is wave-uniform base + lane*16B.
__device__ __forceinline__ void ld_lds16(const u16* g, u16* l) {
    __builtin_amdgcn_global_load_lds(
        (__attribute__((address_space(1))) void*)(uintptr_t)(const void*)g,
        (__attribute__((address_space(3))) void*)l, 16, 0, 0);
}

// ---------------------------------------------------------------------------
// Weight pre-pack: f32 -> bf16, segments laid out contiguously in ws.
// [w1r 655360 | w1t 655360 | w2r 163840 | w2t 163840 | w3r 32768 | w3t 32768]
// ---------------------------------------------------------------------------
__global__ void pack_w_k(const float* __restrict__ w1r, const float* __restrict__ w1t,
                         const float* __restrict__ w2r, const float* __restrict__ w2t,
                         const float* __restrict__ w3r, const float* __restrict__ w3t,
                         u16* __restrict__ dst)
{
    size_t i = (size_t)blockIdx.x * 2048 + (size_t)threadIdx.x * 8;
    const float* src; size_t off;
    if (i < 655360)       { src = w1r; off = 0; }
    else if (i < 1310720) { src = w1t; off = 655360; }
    else if (i < 1474560) { src = w2r; off = 1310720; }
    else if (i < 1638400) { src = w2t; off = 1474560; }
    else if (i < 1671168) { src = w3r; off = 1638400; }
    else                  { src = w3t; off = 1671168; }
    const float4 lo = *(const float4*)(src + (i - off));
    const float4 hi = *(const float4*)(src + (i - off) + 4);
    ushort4 o0, o1;
    o0.x = f2b(lo.x); o0.y = f2b(lo.y); o0.z = f2b(lo.z); o0.w = f2b(lo.w);
    o1.x = f2b(hi.x); o1.y = f2b(hi.y); o1.z = f2b(hi.z); o1.w = f2b(hi.w);
    *(ushort4*)(dst + i) = o0;
    *(ushort4*)(dst + i + 4) = o1;
}

// ---------------------------------------------------------------------------
// 1-NN (f32, mimics np: d2 = rr[i] + qq[j] - 2*g), atomicMin on (d2||idx) key.
// ---------------------------------------------------------------------------
__global__ void knn_k(const float* __restrict__ t1, const float* __restrict__ t2,
                      unsigned long long* __restrict__ keys)
{
    __shared__ float4 ref[128];   // x,y,z,rr
    const int t = threadIdx.x;
    const int rs = blockIdx.x;
    const int qb = blockIdx.y;
    if (t < 128) {
        int i = rs * 128 + t;
        float x = t1[i], y = t1[8192 + i], z = t1[16384 + i];
        float rr = __fadd_rn(__fadd_rn(__fmul_rn(x, x), __fmul_rn(y, y)), __fmul_rn(z, z));
        ref[t] = make_float4(x, y, z, rr);
    }
    __syncthreads();

    float qx[8], qy[8], qz[8], qq[8], bestd[8];
    int besti[8];
    const int q0 = qb * 2048 + t;
#pragma unroll
    for (int j = 0; j < 8; ++j) {
        int q = q0 + j * 256;
        qx[j] = t2[q]; qy[j] = t2[8192 + q]; qz[j] = t2[16384 + q];
        qq[j] = __fadd_rn(__fadd_rn(__fmul_rn(qx[j], qx[j]), __fmul_rn(qy[j], qy[j])),
                          __fmul_rn(qz[j], qz[j]));
        bestd[j] = __uint_as_float(0x7f800000u);
        besti[j] = 0;
    }
    for (int i = 0; i < 128; ++i) {
        float4 r = ref[i];
        int ridx = rs * 128 + i;
#pragma unroll
        for (int j = 0; j < 8; ++j) {
            float g = __fmaf_rn(qz[j], r.z, __fmaf_rn(qy[j], r.y, __fmul_rn(qx[j], r.x)));
            float d2 = __fsub_rn(__fadd_rn(r.w, qq[j]), __fmul_rn(2.0f, g));
            if (d2 < bestd[j]) { bestd[j] = d2; besti[j] = ridx; }
        }
    }
#pragma unroll
    for (int j = 0; j < 8; ++j) {
        unsigned long long key =
            ((unsigned long long)__float_as_uint(bestd[j]) << 32) | (unsigned int)besti[j];
        atomicMin(&keys[q0 + j * 256], key);
    }
}

// ---------------------------------------------------------------------------
// Both transposes in one dispatch: z=0 emb1->emb1t(512), z=1 emb2->Xt cols 512+.
// ---------------------------------------------------------------------------
__global__ void transpose_k(const float* __restrict__ e1, const float* __restrict__ e2,
                            u16* __restrict__ o1, u16* __restrict__ o2)
{
    __shared__ float tile[64][65];
    const float* in = blockIdx.z ? e2 : e1;
    u16* out = blockIdx.z ? o2 : o1;
    const int ostride = blockIdx.z ? 1024 : 512;
    const int coff = blockIdx.z ? 512 : 0;
    const int t = threadIdx.x;
    const int n0 = blockIdx.x * 64, f0 = blockIdx.y * 64;
    const int c = t & 63, r4 = t >> 6;
#pragma unroll
    for (int p = 0; p < 16; ++p) {
        int fr = p * 4 + r4;
        tile[fr][c] = in[(size_t)(f0 + fr) * 8192 + n0 + c];
    }
    __syncthreads();
    const int fc = (t & 15) * 4;    // f-chunk of 4
    const int nr4 = t >> 4;         // 16 n-rows covered per pass
#pragma unroll
    for (int p = 0; p < 4; ++p) {
        int nr = p * 16 + nr4;
        ushort4 o;
        o.x = f2b(tile[fc + 0][nr]); o.y = f2b(tile[fc + 1][nr]);
        o.z = f2b(tile[fc + 2][nr]); o.w = f2b(tile[fc + 3][nr]);
        *(ushort4*)&out[(size_t)(n0 + nr) * ostride + coff + f0 + fc] = o;
    }
}

// ---------------------------------------------------------------------------
// Gather: Xt[n][0:512] = emb1t[idx[n]][0:512]. One wave per row (1KB).
// ---------------------------------------------------------------------------
__global__ void gather_k(const unsigned long long* __restrict__ keys,
                         const u16* __restrict__ emb1t, u16* __restrict__ Xt)
{
    const int t = threadIdx.x, w = t >> 6, l = t & 63;
    const int nbase = blockIdx.x * 32;
#pragma unroll
    for (int it = 0; it < 8; ++it) {
        int n = nbase + it * 4 + w;
        int i = (int)(keys[n] & 0xffffffffu);
        const uint4* src = (const uint4*)(emb1t + (size_t)i * 512);
        uint4* dst = (uint4*)(Xt + (size_t)n * 1024);
        dst[l] = src[l];
    }
}

// ---------------------------------------------------------------------------
// GEMM (BT): Ct[n][out_off+m] = act( sum_k A[m][k]*Bt[n][b_off+k] + bias[m] )
// A: bf16 (Mh x K) row-major (pre-packed). Bt: bf16 (8192 x bstride).
// 128m x TNn tile, BK=32, global_load_lds staging (m97 structure).
// ---------------------------------------------------------------------------
template <int TN>
__global__ __launch_bounds__(256) void gemm_bt(
    const u16* __restrict__ Ar, const u16* __restrict__ At,
    const float* __restrict__ biasr, const float* __restrict__ biast,
    const u16* __restrict__ Bt, u16* __restrict__ Ct,
    int Mh, int K, int bstride, int b_step, int ostride, int relu)
{
    constexpr int NJ = TN / 32;               // 4 or 2
    __shared__ __align__(16) u16 lds_a[128 * 32];
    __shared__ __align__(16) u16 lds_b[TN * 32];

    const int t = threadIdx.x;
    const int n0 = blockIdx.x * TN;
    const int m0 = blockIdx.y * 128;
    const int branch = blockIdx.z;

    const u16* A = branch ? At : Ar;
    const float* bias = branch ? biast : biasr;
    const int b_off = branch * b_step;
    const int out_off = branch * Mh;

    const int w = t >> 6, l = t & 63;
    const int sr = l >> 2, sc = (l & 3) * 8;

    const u16* gA0 = A + (size_t)(m0 + w * 32 + sr) * K + sc;
    const u16* gA1 = gA0 + (size_t)16 * K;
    u16* lA0 = &lds_a[w * 1024];
    u16* lA1 = lA0 + 512;

    const u16* gB0;
    const u16* gB1 = nullptr;
    u16 *lB0, *lB1 = nullptr;
    if (TN == 128) {
        gB0 = Bt + (size_t)(n0 + w * 32 + sr) * bstride + b_off + sc;
        gB1 = gB0 + (size_t)16 * bstride;
        lB0 = &lds_b[w * 1024];
        lB1 = lB0 + 512;
    } else {
        gB0 = Bt + (size_t)(n0 + w * 16 + sr) * bstride + b_off + sc;
        lB0 = &lds_b[w * 512];
    }

    const int wm = (w & 1) * 64;
    const int wn = (w >> 1) * (TN / 2);
    const int lrow = l & 15, quad = l >> 4;
    const u16* fa = &lds_a[(wm + lrow) * 32 + quad * 8];
    const u16* fb = &lds_b[(wn + lrow) * 32 + quad * 8];

    f32x4 acc[4][NJ];
#pragma unroll
    for (int i = 0; i < 4; ++i)
#pragma unroll
        for (int j = 0; j < NJ; ++j)
            acc[i][j] = (f32x4){0.f, 0.f, 0.f, 0.f};

    ld_lds16(gA0, lA0); ld_lds16(gA1, lA1);
    ld_lds16(gB0, lB0);
    if (TN == 128) ld_lds16(gB1, lB1);

    for (int kt = 0; kt < K; kt += 32) {
        __syncthreads();
        bf16x8 af[4], bfr[NJ];
#pragma unroll
        for (int i = 0; i < 4; ++i) af[i] = *(const bf16x8*)(fa + i * 16 * 32);
#pragma unroll
        for (int j = 0; j < NJ; ++j) bfr[j] = *(const bf16x8*)(fb + j * 16 * 32);
        __syncthreads();
        if (kt + 32 < K) {
            gA0 += 32; gA1 += 32; gB0 += 32;
            ld_lds16(gA0, lA0); ld_lds16(gA1, lA1);
            ld_lds16(gB0, lB0);
            if (TN == 128) { gB1 += 32; ld_lds16(gB1, lB1); }
        }
#pragma unroll
        for (int i = 0; i < 4; ++i)
#pragma unroll
            for (int j = 0; j < NJ; ++j)
                acc[i][j] = __builtin_amdgcn_mfma_f32_16x16x32_bf16(
                    af[i], bfr[j], acc[i][j], 0, 0, 0);
    }

    // epilogue: D row m = quad*4+reg, col n = lrow
#pragma unroll
    for (int i = 0; i < 4; ++i) {
        const int mbase = m0 + wm + i * 16 + quad * 4;
        const float4 bbv = *(const float4*)&bias[mbase];
#pragma unroll
        for (int j = 0; j < NJ; ++j) {
            const int n = n0 + wn + j * 16 + lrow;
            f32x4 v = acc[i][j];
            float x0 = v[0] + bbv.x, x1 = v[1] + bbv.y;
            float x2 = v[2] + bbv.z, x3 = v[3] + bbv.w;
            if (relu) {
                x0 = fmaxf(x0, 0.f); x1 = fmaxf(x1, 0.f);
                x2 = fmaxf(x2, 0.f); x3 = fmaxf(x3, 0.f);
            }
            ushort4 o;
            o.x = f2b(x0); o.y = f2b(x1); o.z = f2b(x2); o.w = f2b(x3);
            *(ushort4*)&Ct[(size_t)n * ostride + out_off + mbase] = o;
        }
    }
}

// ---------------------------------------------------------------------------
// Fused layer 3 + layer 4 + slice + transpose + concat.
// Grid (128, 2): 64-n-row tile, branch = blockIdx.y. K=256, full M=128 per
// block -> whole h3 segment lives in this block's acc; layer 4 (7 obj rows)
// computed from f32 h3 in LDS (stride 132: conflict-free), output f32 direct.
// out[0:32768) = rx n*4+k ; out[32768:57344) = tx n*3+k.
// ---------------------------------------------------------------------------
__global__ __launch_bounds__(256) void gemm3_final_k(
    const u16* __restrict__ Ar, const u16* __restrict__ At,
    const float* __restrict__ b3r, const float* __restrict__ b3t,
    const u16* __restrict__ Bt,          // h2t, stride 512
    const float* __restrict__ w4r, const float* __restrict__ b4r,
    const float* __restrict__ w4t, const float* __restrict__ b4t,
    const int* __restrict__ objp, float* __restrict__ out)
{
    __shared__ __align__(16) u16 lds_a[128 * 32];
    __shared__ __align__(16) u16 lds_b[64 * 32];
    __shared__ __align__(16) float lds_h[64 * 132];  // h3 f32, padded stride
    __shared__ __align__(16) float lds_w[4 * 132];   // obj-selected w4 rows

    const int t = threadIdx.x;
    const int n0 = blockIdx.x * 64;
    const int branch = blockIdx.y;

    const u16* A = branch ? At : Ar;
    const float* bias = branch ? b3t : b3r;
    const int b_off = branch * 256;

    const int w = t >> 6, l = t & 63;
    const int sr = l >> 2, sc = (l & 3) * 8;

    const u16* gA0 = A + (size_t)(w * 32 + sr) * 256 + sc;
    const u16* gA1 = gA0 + (size_t)16 * 256;
    u16* lA0 = &lds_a[w * 1024];
    u16* lA1 = lA0 + 512;

    const u16* gB0 = Bt + (size_t)(n0 + w * 16 + sr) * 512 + b_off + sc;
    u16* lB0 = &lds_b[w * 512];

    const int wm = (w & 1) * 64;
    const int wn = (w >> 1) * 32;
    const int lrow = l & 15, quad = l >> 4;
    const u16* fa = &lds_a[(wm + lrow) * 32 + quad * 8];
    const u16* fb = &lds_b[(wn + lrow) * 32 + quad * 8];

    f32x4 acc[4][2];
#pragma unroll
    for (int i = 0; i < 4; ++i)
#pragma unroll
        for (int j = 0; j < 2; ++j)
            acc[i][j] = (f32x4){0.f, 0.f, 0.f, 0.f};

    ld_lds16(gA0, lA0); ld_lds16(gA1, lA1);
    ld_lds16(gB0, lB0);

    for (int kt = 0; kt < 256; kt += 32) {
        __syncthreads();
        bf16x8 af[4], bfr[2];
#pragma unroll
        for (int i = 0; i < 4; ++i) af[i] = *(const bf16x8*)(fa + i * 16 * 32);
#pragma unroll
        for (int j = 0; j < 2; ++j) bfr[j] = *(const bf16x8*)(fb + j * 16 * 32);
        __syncthreads();
        if (kt + 32 < 256) {
            gA0 += 32; gA1 += 32; gB0 += 32;
            ld_lds16(gA0, lA0); ld_lds16(gA1, lA1);
            ld_lds16(gB0, lB0);
        }
#pragma unroll
        for (int i = 0; i < 4; ++i)
#pragma unroll
            for (int j = 0; j < 2; ++j)
                acc[i][j] = __builtin_amdgcn_mfma_f32_16x16x32_bf16(
                    af[i], bfr[j], acc[i][j], 0, 0, 0);
    }

    // ---- h3 (f32, relu) -> LDS ----
#pragma unroll
    for (int i = 0; i < 4; ++i) {
        const int mbase = wm + i * 16 + quad * 4;
        const float4 bbv = *(const float4*)&bias[mbase];
#pragma unroll
        for (int j = 0; j < 2; ++j) {
            const int nl = wn + j * 16 + lrow;
            f32x4 v = acc[i][j];
            float4 x;
            x.x = fmaxf(v[0] + bbv.x, 0.f); x.y = fmaxf(v[1] + bbv.y, 0.f);
            x.z = fmaxf(v[2] + bbv.z, 0.f); x.w = fmaxf(v[3] + bbv.w, 0.f);
            *(float4*)&lds_h[nl * 132 + mbase] = x;
        }
    }
    // ---- obj-selected w4 rows -> LDS ----
    const int o = objp[0];
    const int NR = branch ? 3 : 4;
    const float* w4 = branch ? w4t : w4r;
    if (t < 128) {
        for (int r = 0; r < NR; ++r)
            lds_w[r * 132 + t] = w4[(size_t)(o * NR + r) * 128 + t];
    }
    __syncthreads();

    // ---- layer 4: thread t -> (n_local = t>>2, k = t&3) ----
    const int nl = t >> 2, k = t & 3;
    if (k < NR) {
        const float4* hp = (const float4*)&lds_h[nl * 132];
        const float4* wp4 = (const float4*)&lds_w[k * 132];
        float s = 0.f;
#pragma unroll
        for (int m4 = 0; m4 < 32; ++m4) {
            float4 h = hp[m4], ww = wp4[m4];
            s = fmaf(h.x, ww.x, s); s = fmaf(h.y, ww.y, s);
            s = fmaf(h.z, ww.z, s); s = fmaf(h.w, ww.w, s);
        }
        const int n = n0 + nl;
        if (branch == 0) out[(size_t)n * 4 + k] = s + b4r[o * 4 + k];
        else             out[32768 + (size_t)n * 3 + k] = s + b4t[o * 3 + k];
    }
}

// ---------------------------------------------------------------------------
extern "C" void kernel_launch(void* const* d_in, const int* in_sizes, int n_in,
                              void* d_out, int out_size, void* d_ws, size_t ws_size,
                              hipStream_t stream)
{
    const float* emb1 = (const float*)d_in[0];
    const float* emb2 = (const float*)d_in[1];
    const float* t1   = (const float*)d_in[2];
    const float* t2   = (const float*)d_in[3];
    const int*   obj  = (const int*)d_in[4];
    const float* w1r = (const float*)d_in[5];  const float* b1r = (const float*)d_in[6];
    const float* w2r = (const float*)d_in[7];  const float* b2r = (const float*)d_in[8];
    const float* w3r = (const float*)d_in[9];  const float* b3r = (const float*)d_in[10];
    const float* w4r = (const float*)d_in[11]; const float* b4r = (const float*)d_in[12];
    const float* w1t = (const float*)d_in[13]; const float* b1t = (const float*)d_in[14];
    const float* w2t = (const float*)d_in[15]; const float* b2t = (const float*)d_in[16];
    const float* w3t = (const float*)d_in[17]; const float* b3t = (const float*)d_in[18];
    const float* w4t = (const float*)d_in[19]; const float* b4t = (const float*)d_in[20];

    char* ws = (char*)d_ws;
    unsigned long long* keys = (unsigned long long*)ws;          // 64 KB
    u16* emb1t = (u16*)(ws + (1u << 16));                        // 8 MB  (8192x512)
    u16* Xt    = (u16*)(ws + (1u << 16) + (8u << 20));           // 16 MB (8192x1024)
    u16* h1t   = (u16*)(ws + (1u << 16) + (24u << 20));          // 20 MB (8192x1280)
    u16* wp    = (u16*)(ws + (1u << 16) + (44u << 20));          // 3.25 MB packed weights
    u16* h2t   = emb1t;   // reuse after gather

    u16* w1rp = wp;            u16* w1tp = wp + 655360;
    u16* w2rp = wp + 1310720;  u16* w2tp = wp + 1474560;
    u16* w3rp = wp + 1638400;  u16* w3tp = wp + 1671168;

    hipMemsetAsync(keys, 0xFF, 8192 * sizeof(unsigned long long), stream);
    pack_w_k<<<832, 256, 0, stream>>>(w1r, w1t, w2r, w2t, w3r, w3t, wp);
    knn_k<<<dim3(64, 4), 256, 0, stream>>>(t1, t2, keys);
    transpose_k<<<dim3(128, 8, 2), 256, 0, stream>>>(emb1, emb2, emb1t, Xt);
    gather_k<<<256, 256, 0, stream>>>(keys, emb1t, Xt);
    gemm_bt<128><<<dim3(64, 5, 2), 256, 0, stream>>>(w1rp, w1tp, b1r, b1t, Xt,  h1t, 640, 1024, 1024,   0, 1280, 1);
    gemm_bt<64><<<dim3(128, 2, 2), 256, 0, stream>>>(w2rp, w2tp, b2r, b2t, h1t, h2t, 256,  640, 1280, 640,  512, 1);
    gemm3_final_k<<<dim3(128, 2), 256, 0, stream>>>(w3rp, w3tp, b3r, b3t, h2t,
                                                    w4r, b4r, w4t, b4t, obj, (float*)d_out);
}